// Round 2
// baseline (445.909 us; speedup 1.0000x reference)
//
#include <hip/hip_runtime.h>
#include <hip/hip_bf16.h>
#include <cstdint>

// AttentionPooling: scores = tanh(x@W1+b1)@W2+b2; per-graph softmax-normalized
// weighted sum of x (global softmax Z cancels per-segment up to EPS ~1e-5 rel).
//
// Kernels:
//  1. prep_w1:      W1 fp32 -> f16, pre-arranged in MFMA B-fragment order (64KB)
//  2. score_kernel: f16 MFMA GEMM [N,256]x[256,128], tanh, dot with W2 -> s[N]
//  3. pool_kernel:  per-segment (batch sorted) softmax + weighted x aggregation

#define H_DIM 256
#define HID   128

typedef _Float16 half8 __attribute__((ext_vector_type(8)));
typedef float floatx4 __attribute__((ext_vector_type(4)));

__device__ __forceinline__ float fast_tanh(float y) {
    // tanh(y) = 1 - 2/(exp(2y)+1); safe at +/-inf
    float e2 = __expf(2.0f * y);
    return 1.0f - 2.0f / (e2 + 1.0f);
}

// ---------------------------------------------------------------- prep_w1
// Fragment-order layout: idx = ((nt*8 + ks)*64 + lane)*8 + j
//   maps to W1[k][n] with k = ks*32 + (lane>>4)*8 + j, n = nt*16 + (lane&15)
__global__ void prep_w1(const float* __restrict__ W1, _Float16* __restrict__ w1h) {
    int idx = blockIdx.x * blockDim.x + threadIdx.x;   // 0..32767
    if (idx >= 8 * 8 * 64 * 8) return;
    int j  = idx & 7;
    int l  = (idx >> 3) & 63;
    int ks = (idx >> 9) & 7;
    int nt = idx >> 12;
    int k = ks * 32 + ((l >> 4) << 3) + j;
    int n = nt * 16 + (l & 15);
    w1h[idx] = (_Float16)W1[k * HID + n];
}

// ---------------------------------------------------------------- score
// 512 threads = 8 waves; each wave computes 32 nodes (2 m-tiles of 16).
// Block covers 256 nodes. K-loop: 8 steps of K=32.
__global__ __launch_bounds__(512, 2) void score_kernel(
    const float* __restrict__ x, const _Float16* __restrict__ w1h,
    const float* __restrict__ b1, const float* __restrict__ W2,
    const float* __restrict__ b2, float* __restrict__ sout, int N)
{
    __shared__ __align__(16) _Float16 w1s[32768];   // 64KB, B-fragment order
    int tid = threadIdx.x;
    {   // linear stage: 4096 uint4
        const uint4* src = (const uint4*)w1h;
        uint4* dst = (uint4*)w1s;
#pragma unroll
        for (int i = 0; i < 8; ++i) dst[tid + i * 512] = src[tid + i * 512];
    }
    __syncthreads();

    int wave = tid >> 6, lane = tid & 63;
    int g = lane >> 4, c = lane & 15;
    int node_base = blockIdx.x * 256 + wave * 32;

    int row0 = node_base + c;        // m-tile 0: row = lane&15
    int row1 = row0 + 16;            // m-tile 1
    if (row0 > N - 1) row0 = N - 1;  // clamp (tail block); stores are guarded
    if (row1 > N - 1) row1 = N - 1;
    const float* xr0 = x + (size_t)row0 * H_DIM;
    const float* xr1 = x + (size_t)row1 * H_DIM;

    floatx4 acc[2][8];
#pragma unroll
    for (int mt = 0; mt < 2; ++mt)
#pragma unroll
        for (int nt = 0; nt < 8; ++nt)
#pragma unroll
            for (int q = 0; q < 4; ++q) acc[mt][nt][q] = 0.0f;

#pragma unroll
    for (int ks = 0; ks < 8; ++ks) {
        int kb = ks * 32 + g * 8;    // k = kb + j, j=0..7
        float4 a0 = *(const float4*)(xr0 + kb);
        float4 a1 = *(const float4*)(xr0 + kb + 4);
        float4 a2 = *(const float4*)(xr1 + kb);
        float4 a3 = *(const float4*)(xr1 + kb + 4);
        half8 af0, af1;
        af0[0] = (_Float16)a0.x; af0[1] = (_Float16)a0.y;
        af0[2] = (_Float16)a0.z; af0[3] = (_Float16)a0.w;
        af0[4] = (_Float16)a1.x; af0[5] = (_Float16)a1.y;
        af0[6] = (_Float16)a1.z; af0[7] = (_Float16)a1.w;
        af1[0] = (_Float16)a2.x; af1[1] = (_Float16)a2.y;
        af1[2] = (_Float16)a2.z; af1[3] = (_Float16)a2.w;
        af1[4] = (_Float16)a3.x; af1[5] = (_Float16)a3.y;
        af1[6] = (_Float16)a3.z; af1[7] = (_Float16)a3.w;
#pragma unroll
        for (int nt = 0; nt < 8; ++nt) {
            half8 bf = *(const half8*)&w1s[((nt * 8 + ks) * 64 + lane) * 8];
            acc[0][nt] = __builtin_amdgcn_mfma_f32_16x16x32_f16(af0, bf, acc[0][nt], 0, 0, 0);
            acc[1][nt] = __builtin_amdgcn_mfma_f32_16x16x32_f16(af1, bf, acc[1][nt], 0, 0, 0);
        }
    }

    // Epilogue: s_node = sum_j tanh(h_j + b1_j)*W2_j + b2
    // D layout: col = lane&15 (+16*nt), row = (lane>>4)*4 + r (+16*mt)
    float b1r[8], w2r[8];
#pragma unroll
    for (int nt = 0; nt < 8; ++nt) {
        b1r[nt] = b1[nt * 16 + c];
        w2r[nt] = W2[nt * 16 + c];
    }
    float b2v = b2[0];

#pragma unroll
    for (int mt = 0; mt < 2; ++mt) {
#pragma unroll
        for (int r = 0; r < 4; ++r) {
            float p = 0.0f;
#pragma unroll
            for (int nt = 0; nt < 8; ++nt)
                p += fast_tanh(acc[mt][nt][r] + b1r[nt]) * w2r[nt];
            // reduce over the 16 lanes of this row-group (cols 0..15)
            p += __shfl_xor(p, 8);
            p += __shfl_xor(p, 4);
            p += __shfl_xor(p, 2);
            p += __shfl_xor(p, 1);
            if (c == 0) {
                int node = node_base + mt * 16 + g * 4 + r;
                if (node < N) sout[node] = p + b2v;
            }
        }
    }
}

// ---------------------------------------------------------------- pool
// One block (256 threads) per graph; thread t owns feature column t.
__global__ __launch_bounds__(256) void pool_kernel(
    const float* __restrict__ x, const float* __restrict__ s,
    const int* __restrict__ batch, float* __restrict__ out, int N, int B)
{
    int b = blockIdx.x;
    int tid = threadIdx.x;

    // segment bounds via binary search (batch is sorted)
    int lo = 0, hi = N;
    while (lo < hi) { int mid = (lo + hi) >> 1; if (batch[mid] < b) lo = mid + 1; else hi = mid; }
    int start = lo;
    hi = N;
    while (lo < hi) { int mid = (lo + hi) >> 1; if (batch[mid] < b + 1) lo = mid + 1; else hi = mid; }
    int end = lo;

    if (start >= end) { out[(size_t)b * H_DIM + tid] = 0.0f; return; }

    __shared__ float red[4];
    __shared__ float bval[2];
    __shared__ float wl[256];
    int wid = tid >> 6, lane = tid & 63;

    // 1. segment max
    float lm = -3.0e38f;
    for (int i = start + tid; i < end; i += 256) lm = fmaxf(lm, s[i]);
#pragma unroll
    for (int off = 32; off; off >>= 1) lm = fmaxf(lm, __shfl_xor(lm, off));
    if (lane == 0) red[wid] = lm;
    __syncthreads();
    if (tid == 0) bval[0] = fmaxf(fmaxf(red[0], red[1]), fmaxf(red[2], red[3]));
    __syncthreads();
    float m = bval[0];

    // 2. segment sum of exp(s - m)
    float lz = 0.0f;
    for (int i = start + tid; i < end; i += 256) lz += __expf(s[i] - m);
#pragma unroll
    for (int off = 32; off; off >>= 1) lz += __shfl_xor(lz, off);
    if (lane == 0) red[wid] = lz;
    __syncthreads();
    if (tid == 0) bval[1] = red[0] + red[1] + red[2] + red[3];
    __syncthreads();
    float Zinv = 1.0f / bval[1];

    // 3. weighted aggregation in chunks of 256 rows
    float acc = 0.0f;
    for (int base = start; base < end; base += 256) {
        __syncthreads();                       // protect wl from prior reads
        int i = base + tid;
        wl[tid] = (i < end) ? __expf(s[i] - m) : 0.0f;
        __syncthreads();
        int cnt = min(256, end - base);
        const float* xp = x + (size_t)base * H_DIM + tid;
        for (int j = 0; j < cnt; ++j)
            acc = fmaf(wl[j], xp[(size_t)j * H_DIM], acc);
    }
    out[(size_t)b * H_DIM + tid] = acc * Zinv;
}

// ---------------------------------------------------------------- launch
extern "C" void kernel_launch(void* const* d_in, const int* in_sizes, int n_in,
                              void* d_out, int out_size, void* d_ws, size_t ws_size,
                              hipStream_t stream) {
    const float* x   = (const float*)d_in[0];
    const float* W1  = (const float*)d_in[1];
    const float* b1  = (const float*)d_in[2];
    const float* W2  = (const float*)d_in[3];
    const float* b2  = (const float*)d_in[4];
    const int*  batch = (const int*)d_in[5];
    int N = in_sizes[5];
    int B = out_size / H_DIM;

    // workspace: s[N] fp32, then frag-ordered W1 f16 (64KB)
    float* s = (float*)d_ws;
    size_t soff = (((size_t)N * sizeof(float)) + 255) & ~(size_t)255;
    _Float16* w1h = (_Float16*)((char*)d_ws + soff);

    prep_w1<<<32768 / 256, 256, 0, stream>>>(W1, w1h);

    int nblk = (N + 255) / 256;
    score_kernel<<<nblk, 512, 0, stream>>>(x, w1h, b1, W2, b2, s, N);

    pool_kernel<<<B, 256, 0, stream>>>(x, s, batch, (float*)d_out, N, B);
}

// Round 3
// 373.753 us; speedup vs baseline: 1.1931x; 1.1931x over previous
//
#include <hip/hip_runtime.h>
#include <hip/hip_bf16.h>
#include <cstdint>

// AttentionPooling, fused single-pass over x (flash-style online softmax per graph).
//  1. prep_w1:  W1 fp32 -> f16 in MFMA B-fragment order (64KB)
//  2. fused_kernel: one block per graph; per 64-row chunk:
//       scores via f16 MFMA (A from global, W1 from LDS) -> online softmax
//       state update -> column-parallel weighted accumulation (global re-read,
//       expected L2-hot). x is fetched from HBM exactly once.

#define H_DIM 256
#define HID   128
#define CHUNK 64

typedef _Float16 half8 __attribute__((ext_vector_type(8)));
typedef float floatx4 __attribute__((ext_vector_type(4)));

__device__ __forceinline__ float fast_tanh(float y) {
    float e2 = __expf(2.0f * y);
    return 1.0f - 2.0f / (e2 + 1.0f);
}

// ---------------------------------------------------------------- prep_w1
// idx = ((nt*8 + ks)*64 + lane)*8 + j  <->  W1[k][n], k = ks*32+(lane>>4)*8+j,
// n = nt*16 + (lane&15)
__global__ void prep_w1(const float* __restrict__ W1, _Float16* __restrict__ w1h) {
    int idx = blockIdx.x * blockDim.x + threadIdx.x;
    if (idx >= 8 * 8 * 64 * 8) return;
    int j  = idx & 7;
    int l  = (idx >> 3) & 63;
    int ks = (idx >> 9) & 7;
    int nt = idx >> 12;
    int k = ks * 32 + ((l >> 4) << 3) + j;
    int n = nt * 16 + (l & 15);
    w1h[idx] = (_Float16)W1[k * HID + n];
}

// ---------------------------------------------------------------- fused
__global__ __launch_bounds__(256, 2) void fused_kernel(
    const float* __restrict__ x, const _Float16* __restrict__ w1h,
    const float* __restrict__ b1, const float* __restrict__ W2,
    const float* __restrict__ b2, const int* __restrict__ batch,
    float* __restrict__ out, int N)
{
    __shared__ __align__(16) _Float16 w1s[32768];   // 64KB B-fragment order
    __shared__ float sbuf[CHUNK];                   // chunk scores
    __shared__ float wbuf[CHUNK];                   // chunk exp-weights
    __shared__ float fstate;                        // rescale factor
    __shared__ float zstate;                        // final Z

    int tid = threadIdx.x;
    int b = blockIdx.x;

    {   // stage W1: 4096 uint4, linear
        const uint4* src = (const uint4*)w1h;
        uint4* dst = (uint4*)w1s;
#pragma unroll
        for (int i = 0; i < 16; ++i) dst[tid + i * 256] = src[tid + i * 256];
    }

    // segment bounds (batch sorted)
    int lo = 0, hi = N;
    while (lo < hi) { int mid = (lo + hi) >> 1; if (batch[mid] < b) lo = mid + 1; else hi = mid; }
    int start = lo; hi = N;
    while (lo < hi) { int mid = (lo + hi) >> 1; if (batch[mid] <= b) lo = mid + 1; else hi = mid; }
    int end = lo;
    int seglen = end - start;

    if (seglen <= 0) { out[(size_t)b * H_DIM + tid] = 0.0f; return; }

    __syncthreads();   // w1s ready

    int wave = tid >> 6, lane = tid & 63;
    int g = lane >> 4, c = lane & 15;

    float b1r[8], w2r[8];
#pragma unroll
    for (int nt = 0; nt < 8; ++nt) { b1r[nt] = b1[nt * 16 + c]; w2r[nt] = W2[nt * 16 + c]; }
    float b2v = b2[0];

    float m_run = -3.0e38f;   // wave0-uniform running max
    float Zrun  = 0.0f;       // wave0-uniform running Z
    float accv  = 0.0f;       // per-thread column accumulator

    for (int co = 0; co < seglen; co += CHUNK) {
        int cnt = min(CHUNK, seglen - co);

        // ---- scores: wave computes its 16 rows, K=256 in 8 steps
        int row = start + co + wave * 16 + c;
        if (row > end - 1) row = end - 1;            // clamp; scores masked below
        const float* xr = x + (size_t)row * H_DIM;

        floatx4 acc[8];
#pragma unroll
        for (int nt = 0; nt < 8; ++nt)
#pragma unroll
            for (int q = 0; q < 4; ++q) acc[nt][q] = 0.0f;

#pragma unroll
        for (int ks = 0; ks < 8; ++ks) {
            int kb = ks * 32 + g * 8;
            float4 a0 = *(const float4*)(xr + kb);
            float4 a1 = *(const float4*)(xr + kb + 4);
            half8 af;
            af[0] = (_Float16)a0.x; af[1] = (_Float16)a0.y;
            af[2] = (_Float16)a0.z; af[3] = (_Float16)a0.w;
            af[4] = (_Float16)a1.x; af[5] = (_Float16)a1.y;
            af[6] = (_Float16)a1.z; af[7] = (_Float16)a1.w;
#pragma unroll
            for (int nt = 0; nt < 8; ++nt) {
                half8 bf = *(const half8*)&w1s[((nt * 8 + ks) * 64 + lane) * 8];
                acc[nt] = __builtin_amdgcn_mfma_f32_16x16x32_f16(af, bf, acc[nt], 0, 0, 0);
            }
        }

        // ---- epilogue: s = sum_j tanh(h_j+b1_j)*W2_j + b2
        // D layout: col = lane&15 (n within tile), row = g*4 + r (m within tile)
#pragma unroll
        for (int r = 0; r < 4; ++r) {
            float p = 0.0f;
#pragma unroll
            for (int nt = 0; nt < 8; ++nt)
                p += fast_tanh(acc[nt][r] + b1r[nt]) * w2r[nt];
            p += __shfl_xor(p, 8);
            p += __shfl_xor(p, 4);
            p += __shfl_xor(p, 2);
            p += __shfl_xor(p, 1);
            if (c == 0) {
                int nl = wave * 16 + g * 4 + r;       // row-local node index
                sbuf[nl] = (nl < cnt) ? (p + b2v) : -3.0e38f;
            }
        }
        __syncthreads();   // (A) sbuf ready; prior wbuf reads complete

        if (wave == 0) {
            float sv = sbuf[lane];
            float cm = sv;
#pragma unroll
            for (int off = 32; off; off >>= 1) cm = fmaxf(cm, __shfl_xor(cm, off));
            float m_new = fmaxf(m_run, cm);
            float f = __expf(m_run - m_new);          // 0 on first chunk
            float w = __expf(sv - m_new);             // 0 for masked rows
            wbuf[lane] = w;
            float sw = w;
#pragma unroll
            for (int off = 32; off; off >>= 1) sw += __shfl_xor(sw, off);
            Zrun = Zrun * f + sw;
            m_run = m_new;
            if (lane == 0) fstate = f;
        }
        __syncthreads();   // (B) wbuf/fstate ready

        // ---- accumulation: thread t owns column t; rows re-read (L2-hot)
        float f = fstate;
        const float* xc = x + (size_t)(start + co) * H_DIM + tid;
        float a = 0.0f;
#pragma unroll 8
        for (int j = 0; j < cnt; ++j)
            a = fmaf(wbuf[j], xc[(size_t)j * H_DIM], a);
        accv = accv * f + a;
    }

    if (tid == 0) zstate = Zrun;
    __syncthreads();
    out[(size_t)b * H_DIM + tid] = accv / zstate;
}

// ---------------------------------------------------------------- launch
extern "C" void kernel_launch(void* const* d_in, const int* in_sizes, int n_in,
                              void* d_out, int out_size, void* d_ws, size_t ws_size,
                              hipStream_t stream) {
    const float* x    = (const float*)d_in[0];
    const float* W1   = (const float*)d_in[1];
    const float* b1   = (const float*)d_in[2];
    const float* W2   = (const float*)d_in[3];
    const float* b2   = (const float*)d_in[4];
    const int*   batch = (const int*)d_in[5];
    int N = in_sizes[5];
    int B = out_size / H_DIM;

    _Float16* w1h = (_Float16*)d_ws;   // 64KB frag-ordered W1

    prep_w1<<<32768 / 256, 256, 0, stream>>>(W1, w1h);
    fused_kernel<<<B, 256, 0, stream>>>(x, w1h, b1, W2, b2, batch, (float*)d_out, N);
}